// Round 7
// baseline (739.953 us; speedup 1.0000x reference)
//
#include <hip/hip_runtime.h>
#include <math.h>

#define QMAXF 32767.0f

typedef short short8v __attribute__((ext_vector_type(8)));
typedef float f32x4 __attribute__((ext_vector_type(4)));

__device__ __forceinline__ float clampf(float v, float lo, float hi) {
    return __builtin_amdgcn_fmed3f(v, lo, hi);
}
__device__ __forceinline__ float fq_code(float x, float s) {
    return clampf(rintf(x / s), -QMAXF, QMAXF);
}

// ---------------- weight prep: 4 independent blocks ----------------
__device__ float block_scale(const float* w, int n, float* red) {
    float m = 0.f;
    for (int i = threadIdx.x; i < n; i += blockDim.x) m = fmaxf(m, fabsf(w[i]));
    red[threadIdx.x] = m; __syncthreads();
    for (int s = blockDim.x >> 1; s > 0; s >>= 1) {
        if ((int)threadIdx.x < s) red[threadIdx.x] = fmaxf(red[threadIdx.x], red[threadIdx.x + s]);
        __syncthreads();
    }
    float r = red[0]; __syncthreads();
    return fmaxf(r / QMAXF, 1e-8f);
}

__device__ void prep_16x16(const float* __restrict__ w, ushort* __restrict__ wqb,
                           float* __restrict__ wsb_slot, float* red) {
    float s = block_scale(w, 2304, red);
    if (threadIdx.x == 0) *wsb_slot = s;
    for (int i = threadIdx.x; i < 2304; i += 256) {
        int co = i / 144, rem = i % 144, cin = rem / 9, t = rem % 9;
        int wc = (int)fq_code(w[i], s);
        uint bh = __float_as_uint((float)(wc & ~127)) >> 16;
        uint bl = __float_as_uint((float)(wc & 127)) >> 16;
        int kb = cin >> 3, j = cin & 7;
        wqb[((t * 4 + kb) * 16 + co) * 8 + j]     = (ushort)bh;
        wqb[((t * 4 + 2 + kb) * 16 + co) * 8 + j] = (ushort)bl;
    }
}

__global__ void prep_kernel(const float* __restrict__ w1, const float* __restrict__ w2,
                            const float* __restrict__ w3, const float* __restrict__ wfc,
                            const float* __restrict__ asc,
                            float* __restrict__ wq1, ushort* __restrict__ wq2b,
                            ushort* __restrict__ wq3b, float* __restrict__ wqfc,
                            float* __restrict__ wsb) {
    __shared__ float red[256];
    const int which = blockIdx.x;
    if (which == 0) {
        float s = block_scale(w1, 144, red);   // [16][1][3][3] -> [tap][16], a0 folded
        float a0 = asc[0];
        for (int i = threadIdx.x; i < 144; i += 256) {
            int co = i / 9, r = i % 9;
            wq1[r * 16 + co] = fq_code(w1[i], s) * s * a0;
        }
    } else if (which == 1) {
        prep_16x16(w2, wq2b, wsb + 0, red);
    } else if (which == 2) {
        prep_16x16(w3, wq3b, wsb + 1, red);
    } else {
        float s = block_scale(wfc, 160, red);
        for (int i = threadIdx.x; i < 160; i += 256) wqfc[i] = fq_code(wfc[i], s) * s;
    }
}

// ---------------- conv1: 1->16 ch (VALU), 8 rows x 112 cols, 2px x 16co/thread ----------------
__global__ __launch_bounds__(448, 6) void conv1_kernel(const float* __restrict__ x,
        const float* __restrict__ wq, const float* __restrict__ bias,
        const float* __restrict__ asc, const float* __restrict__ shf,
        ushort* __restrict__ out) {
    const int bid = blockIdx.x;
    const int b = bid / 56, rem = bid % 56, rg = rem >> 1, chh = rem & 1;
    const int r0 = rg * 8, c0 = chh * 112;
    const int tid = threadIdx.x;
    __shared__ alignas(16) short lx[10 * 120];   // x[ic] at col (ic-c0+1); row stride 120
    __shared__ alignas(16) float lw[144];
    __shared__ float lbsc[16];
    const float a0 = asc[0], a1 = asc[1];
    const float r0a = 1.0f / a0;
    const float sh = clampf(rintf(shf[0]), 4.f, 12.f);
    const float sc = exp2f(sh), osc = exp2f(-sh);
    const float three = 3.f * sc, six = 6.f * sc;
    const float r6 = 1.0f / six;
    const float rq1 = osc / a1;
    const float* xb = x + (size_t)b * 50176;
    for (int i = tid; i < 1140; i += 448) {
        int r = i / 114, cc = i - r * 114;
        int ir = r0 - 1 + r, ic = c0 - 1 + cc;
        float v = ((unsigned)ir < 224u && (unsigned)ic < 224u) ? xb[ir * 224 + ic] : 0.f;
        lx[r * 120 + cc] = (short)clampf(rintf(v * r0a), -QMAXF, QMAXF);
    }
    for (int i = tid; i < 144; i += 448) lw[i] = wq[i];
    if (tid < 16) lbsc[tid] = bias[tid] * sc;
    __syncthreads();
    const int row = tid / 56, pc = (tid - row * 56) * 2;
    float acc[2][16];
#pragma unroll
    for (int p = 0; p < 2; p++)
#pragma unroll
        for (int j = 0; j < 16; j++) acc[p][j] = 0.f;
#pragma unroll
    for (int ky = 0; ky < 3; ky++) {
        const short* rp = lx + (row + ky) * 120 + pc;
        int i0 = *(const int*)(rp);
        int i1 = *(const int*)(rp + 2);
        float xf[4];
        xf[0] = (float)(short)(i0 & 0xffff);
        xf[1] = (float)(i0 >> 16);
        xf[2] = (float)(short)(i1 & 0xffff);
        xf[3] = (float)(i1 >> 16);
#pragma unroll
        for (int kx = 0; kx < 3; kx++) {
            const float* wp = &lw[(ky * 3 + kx) * 16];
#pragma unroll
            for (int p = 0; p < 2; p++) {
                float xv = xf[p + kx];
#pragma unroll
                for (int j = 0; j < 16; j++)
                    acc[p][j] = fmaf(xv, wp[j], acc[p][j]);
            }
        }
    }
    const int orow = r0 + row;
    const size_t obase = ((size_t)b * 224 + orow) * 224 + c0 + pc;   // pixel index
#pragma unroll
    for (int p = 0; p < 2; p++) {
        uint pk[8];
#pragma unroll
        for (int j = 0; j < 16; j++) {
            float xi = clampf(rintf(fmaf(acc[p][j], sc, lbsc[j])), -32768.f, 32767.f);
            float slope = rintf(xi * 1.703125f);
            float gate = clampf(slope + three, 0.f, six);
            float k = clampf(rintf(xi * gate * r6), -QMAXF, QMAXF);
            int cd = (int)clampf(rintf(k * rq1), -QMAXF, QMAXF);
            if (j & 1) pk[j >> 1] |= ((uint)cd) << 16;
            else       pk[j >> 1] = (uint)cd & 0xffffu;
        }
        uint4* dst = (uint4*)(out + (obase + p) * 16);
        dst[0] = make_uint4(pk[0], pk[1], pk[2], pk[3]);
        dst[1] = make_uint4(pk[4], pk[5], pk[6], pk[7]);
    }
}

// ---------------- conv2/conv3: MFMA implicit GEMM (D = W * X), 8 rows x 112 cols ----------------
// Pipelined: MFMA of tile cg overlaps epilogue of tile cg-1 (double-buffered acc sets,
// 4 independent chains per set). LDS layout/swizzle as round 4/6 (zero conflicts measured).
template <bool POOL>
__global__ __launch_bounds__(512, 4) void conv16_kernel(
        const ushort* __restrict__ in, const ushort* __restrict__ wq,
        const float* __restrict__ bias, const float* __restrict__ asc,
        const float* __restrict__ shf, const float* __restrict__ wsb,
        ushort* __restrict__ out, float* __restrict__ partial,
        int aidx, int sidx, int widx) {
    const int bid = blockIdx.x;
    const int b = bid / 56, rem = bid % 56, rg = rem >> 1, ch = rem & 1;
    const int r0 = rg * 8, c0 = ch * 112;
    const int tid = threadIdx.x;
    const int l = tid & 63, w = tid >> 6;
    const int l15 = l & 15, lk = l >> 4;

    __shared__ alignas(16) ushort lsx[1140 * 32];       // 72,960 B (10 rows x 114 cols)
    __shared__ float lred[8][16];

    const float ain = asc[aidx];
    const float anext = asc[aidx + 1];
    const float wsc = wsb[widx];
    const float sh = clampf(rintf(shf[sidx]), 4.f, 12.f);
    const float sc = exp2f(sh), osc = exp2f(-sh);
    const float three = 3.f * sc, six = 6.f * sc;
    const float gs2 = (ain * wsc) * sc;
    const float r6 = 1.0f / six;
    const float rq = osc / anext;
    float bsc[4];
#pragma unroll
    for (int r = 0; r < 4; r++) bsc[r] = bias[lk * 4 + r] * sc;

    // ---- W fragments (A operand): pass1 [wh|wl], pass2 [wl|wh] ----
    short8v B1[9], B2[9];
#pragma unroll
    for (int t = 0; t < 9; t++) {
        B1[t] = *(const short8v*)(wq + ((t * 4 + lk) * 16 + l15) * 8);
        B2[t] = *(const short8v*)(wq + ((t * 4 + (lk ^ 2)) * 16 + l15) * 8);
    }

    // ---- stage x tile: 10 rows x 114 cols; RTZ bf16 hi/lo split (exact) ----
#pragma unroll
    for (int it = 0; it < 3; it++) {
        int e = tid + it * 512;
        if (e < 1140) {
            int r = e / 114, cc = e - r * 114;
            int ir = r0 - 1 + r, ic = c0 - 1 + cc;
            uint4 va = make_uint4(0u, 0u, 0u, 0u), vb = make_uint4(0u, 0u, 0u, 0u);
            if ((unsigned)ir < 224u && (unsigned)ic < 224u) {
                const uint4* src = (const uint4*)(in + (((size_t)b * 224 + ir) * 224 + ic) * 16);
                va = src[0]; vb = src[1];
            }
            uint uu[8] = {va.x, va.y, va.z, va.w, vb.x, vb.y, vb.z, vb.w};
            uint hi[8], lo[8];
#pragma unroll
            for (int i = 0; i < 8; i++) {
                int e0 = (int)(short)(uu[i] & 0xffffu);
                int e1 = (int)uu[i] >> 16;
                float f0 = (float)e0, f1 = (float)e1;
                uint h0 = __float_as_uint(f0) & 0xffff0000u;
                uint h1 = __float_as_uint(f1) & 0xffff0000u;
                float l0f = f0 - __uint_as_float(h0);   // exact, fits bf16
                float l1f = f1 - __uint_as_float(h1);
                hi[i] = __builtin_amdgcn_perm(h1, h0, 0x07060302);
                lo[i] = __builtin_amdgcn_perm(__float_as_uint(l1f), __float_as_uint(l0f), 0x07060302);
            }
            int rot = (e >> 1) & 3;
            ushort* eb = lsx + e * 32;
            *(uint4*)(eb + ((0 ^ rot) << 3)) = make_uint4(hi[0], hi[1], hi[2], hi[3]);
            *(uint4*)(eb + ((1 ^ rot) << 3)) = make_uint4(hi[4], hi[5], hi[6], hi[7]);
            *(uint4*)(eb + ((2 ^ rot) << 3)) = make_uint4(lo[0], lo[1], lo[2], lo[3]);
            *(uint4*)(eb + ((3 ^ rot) << 3)) = make_uint4(lo[4], lo[5], lo[6], lo[7]);
        }
    }
    __syncthreads();

    // ---- per-lane swizzled base pointers (rot invariant under +114-entry ky step
    //      and +16-entry cg step) ----
    const ushort* Ab[7];
#pragma unroll
    for (int m = 0; m < 7; m++) {
        int e = w * 114 + l15 + m;
        Ab[m] = lsx + e * 32 + ((lk ^ ((e >> 1) & 3)) << 3);
    }

    float wsum[4] = {0.f, 0.f, 0.f, 0.f};
    const int orow = r0 + w;
    ushort* opb = out + (((size_t)b * 224 + orow) * 224 + c0 + l15) * 16 + lk * 4;

    auto epi = [&](const f32x4* a4, int cgi) {
        int cd[4];
#pragma unroll
        for (int r = 0; r < 4; r++) {
            float s = (a4[0][r] + a4[1][r]) + (a4[2][r] + a4[3][r]);
            float xi = clampf(rintf(fmaf(s, gs2, bsc[r])), -32768.f, 32767.f);
            float slope = rintf(xi * 1.703125f);
            float gate = clampf(slope + three, 0.f, six);
            float k = clampf(rintf(xi * gate * r6), -QMAXF, QMAXF);
            if (!POOL) cd[r] = (int)clampf(rintf(k * rq), -QMAXF, QMAXF);
            else       wsum[r] += k;
        }
        if (!POOL) {
            uint2 st;
            st.x = ((uint)cd[0] & 0xffffu) | ((uint)cd[1] << 16);
            st.y = ((uint)cd[2] & 0xffffu) | ((uint)cd[3] << 16);
            *(uint2*)(opb + cgi * 256) = st;
        }
    };

    const f32x4 Z = {0.f, 0.f, 0.f, 0.f};
    f32x4 acc[2][4];
#pragma unroll
    for (int cg = 0; cg < 7; cg++) {
        const int s = cg & 1;
        short8v af[9];
#pragma unroll
        for (int ky = 0; ky < 3; ky++)
#pragma unroll
            for (int kx = 0; kx < 3; kx++)
                af[ky * 3 + kx] = *(const short8v*)(Ab[2 * ky + kx] + 3584 * ky + 512 * cg);
#pragma unroll
        for (int t = 0; t < 9; t++) {
            const int c1 = t & 1, c2 = 2 + (t & 1);
            acc[s][c1] = __builtin_amdgcn_mfma_f32_16x16x32_bf16(B1[t], af[t],
                             (t < 2) ? Z : acc[s][c1], 0, 0, 0);
            acc[s][c2] = __builtin_amdgcn_mfma_f32_16x16x32_bf16(B2[t], af[t],
                             (t < 2) ? Z : acc[s][c2], 0, 0, 0);
        }
        if (cg > 0) epi(acc[s ^ 1], cg - 1);    // epilogue of prev tile under this tile's MFMA
    }
    epi(acc[0], 6);                              // cg=6 used set 0

    if (POOL) {
#pragma unroll
        for (int r = 0; r < 4; r++) {
            float v = wsum[r] * osc;
            v += __shfl_xor(v, 1);
            v += __shfl_xor(v, 2);
            v += __shfl_xor(v, 4);
            v += __shfl_xor(v, 8);
            if (l15 == 0) lred[w][lk * 4 + r] = v;
        }
        __syncthreads();
        if (tid < 16) {
            float t = 0.f;
#pragma unroll
            for (int q = 0; q < 8; q++) t += lred[q][tid];
            partial[((size_t)b * 56 + rem) * 16 + tid] = t;
        }
    }
}

// ---------------- pool-reduce + quantized FC ----------------
__global__ __launch_bounds__(1024) void fc_kernel(const float* __restrict__ partial,
        const float* __restrict__ wq, const float* __restrict__ fb,
        const float* __restrict__ asc, float* __restrict__ out) {
    __shared__ float xq[64][16];
    const int t = threadIdx.x;
    const float a3 = asc[3];
    {
        int b = t >> 4, c = t & 15;
        const float* p = partial + ((size_t)b * 56) * 16 + c;
        float s = 0.f;
        for (int i = 0; i < 56; i++) s += p[i * 16];
        float pooled = s / 50176.0f;
        xq[b][c] = fq_code(pooled, a3) * a3;
    }
    __syncthreads();
    if (t < 640) {
        int b = t / 10, o = t - (t / 10) * 10;
        float s = 0.f;
#pragma unroll
        for (int c = 0; c < 16; c++) s += xq[b][c] * wq[o * 16 + c];
        out[t] = s + fb[o];
    }
}

extern "C" void kernel_launch(void* const* d_in, const int* in_sizes, int n_in,
                              void* d_out, int out_size, void* d_ws, size_t ws_size,
                              hipStream_t stream) {
    const float* x   = (const float*)d_in[0];
    const float* c1w = (const float*)d_in[1];
    const float* c1b = (const float*)d_in[2];
    const float* c2w = (const float*)d_in[3];
    const float* c2b = (const float*)d_in[4];
    const float* c3w = (const float*)d_in[5];
    const float* c3b = (const float*)d_in[6];
    const float* fcw = (const float*)d_in[7];
    const float* fcb = (const float*)d_in[8];
    const float* asc = (const float*)d_in[9];
    const float* shf = (const float*)d_in[10];

    char* ws = (char*)d_ws;
    size_t off = 0;
    auto alloc = [&](size_t bytes) -> void* {
        void* p = ws + off;
        off = (off + bytes + 255) & ~(size_t)255;
        return p;
    };
    float*  wq1     = (float*)alloc(144 * 4);
    ushort* wq2b    = (ushort*)alloc(4608 * 2);
    ushort* wq3b    = (ushort*)alloc(4608 * 2);
    float*  wqfc    = (float*)alloc(160 * 4);
    float*  wsb     = (float*)alloc(4 * 4);
    float*  partial = (float*)alloc(64 * 56 * 16 * 4);
    ushort* actA    = (ushort*)alloc(51380224ull * 2);
    ushort* actB    = (ushort*)alloc(51380224ull * 2);

    prep_kernel<<<4, 256, 0, stream>>>(c1w, c2w, c3w, fcw, asc, wq1, wq2b, wq3b, wqfc, wsb);
    conv1_kernel<<<3584, 448, 0, stream>>>(x, wq1, c1b, asc, shf, actA);
    conv16_kernel<false><<<3584, 512, 0, stream>>>(actA, wq2b, c2b, asc, shf, wsb,
                                                   actB, nullptr, 1, 1, 0);
    conv16_kernel<true ><<<3584, 512, 0, stream>>>(actB, wq3b, c3b, asc, shf, wsb,
                                                   nullptr, partial, 2, 2, 1);
    fc_kernel<<<1, 1024, 0, stream>>>(partial, wqfc, fcb, asc, (float*)d_out);
}

// Round 8
// 291.450 us; speedup vs baseline: 2.5389x; 2.5389x over previous
//
#include <hip/hip_runtime.h>
#include <math.h>

#define QMAXF 32767.0f

typedef short short8v __attribute__((ext_vector_type(8)));
typedef float f32x4 __attribute__((ext_vector_type(4)));

__device__ __forceinline__ float clampf(float v, float lo, float hi) {
    return __builtin_amdgcn_fmed3f(v, lo, hi);
}
__device__ __forceinline__ float fq_code(float x, float s) {
    return clampf(rintf(x / s), -QMAXF, QMAXF);
}

// ---------------- weight prep: 4 independent blocks ----------------
__device__ float block_scale(const float* w, int n, float* red) {
    float m = 0.f;
    for (int i = threadIdx.x; i < n; i += blockDim.x) m = fmaxf(m, fabsf(w[i]));
    red[threadIdx.x] = m; __syncthreads();
    for (int s = blockDim.x >> 1; s > 0; s >>= 1) {
        if ((int)threadIdx.x < s) red[threadIdx.x] = fmaxf(red[threadIdx.x], red[threadIdx.x + s]);
        __syncthreads();
    }
    float r = red[0]; __syncthreads();
    return fmaxf(r / QMAXF, 1e-8f);
}

__device__ void prep_16x16(const float* __restrict__ w, ushort* __restrict__ wqb,
                           float* __restrict__ wsb_slot, float* red) {
    float s = block_scale(w, 2304, red);
    if (threadIdx.x == 0) *wsb_slot = s;
    for (int i = threadIdx.x; i < 2304; i += 256) {
        int co = i / 144, rem = i % 144, cin = rem / 9, t = rem % 9;
        int wc = (int)fq_code(w[i], s);
        uint bh = __float_as_uint((float)(wc & ~127)) >> 16;
        uint bl = __float_as_uint((float)(wc & 127)) >> 16;
        int kb = cin >> 3, j = cin & 7;
        wqb[((t * 4 + kb) * 16 + co) * 8 + j]     = (ushort)bh;
        wqb[((t * 4 + 2 + kb) * 16 + co) * 8 + j] = (ushort)bl;
    }
}

__global__ void prep_kernel(const float* __restrict__ w1, const float* __restrict__ w2,
                            const float* __restrict__ w3, const float* __restrict__ wfc,
                            const float* __restrict__ asc,
                            float* __restrict__ wq1, ushort* __restrict__ wq2b,
                            ushort* __restrict__ wq3b, float* __restrict__ wqfc,
                            float* __restrict__ wsb) {
    __shared__ float red[256];
    const int which = blockIdx.x;
    if (which == 0) {
        float s = block_scale(w1, 144, red);   // [16][1][3][3] -> [tap][16], a0 folded
        float a0 = asc[0];
        for (int i = threadIdx.x; i < 144; i += 256) {
            int co = i / 9, r = i % 9;
            wq1[r * 16 + co] = fq_code(w1[i], s) * s * a0;
        }
    } else if (which == 1) {
        prep_16x16(w2, wq2b, wsb + 0, red);
    } else if (which == 2) {
        prep_16x16(w3, wq3b, wsb + 1, red);
    } else {
        float s = block_scale(wfc, 160, red);
        for (int i = threadIdx.x; i < 160; i += 256) wqfc[i] = fq_code(wfc[i], s) * s;
    }
}

// ---------------- conv1: 1->16 ch (VALU), 8 rows x 224 cols (round-4 proven) ----------------
__global__ __launch_bounds__(448) void conv1_kernel(const float* __restrict__ x,
        const float* __restrict__ wq, const float* __restrict__ bias,
        const float* __restrict__ asc, const float* __restrict__ shf,
        ushort* __restrict__ out) {
    const int bid = blockIdx.x;
    const int b = bid / 28, rt = bid % 28, r0 = rt * 8;
    const int tid = threadIdx.x;
    __shared__ alignas(16) short lx[10][224];
    __shared__ alignas(16) float lw[144];
    __shared__ float lbsc[16];
    const float a0 = asc[0], a1 = asc[1];
    const float r0a = 1.0f / a0;
    const float sh = clampf(rintf(shf[0]), 4.f, 12.f);
    const float sc = exp2f(sh), osc = exp2f(-sh);
    const float three = 3.f * sc, six = 6.f * sc;
    const float r6v = 1.0f / six;
    const float rq1 = osc / a1;
    const float* xb = x + (size_t)b * 50176;
    for (int i = tid; i < 2240; i += 448) {
        int r = i / 224, c = i - r * 224, sr = r0 - 1 + r;
        float v = (sr >= 0 && sr < 224) ? xb[sr * 224 + c] : 0.f;
        lx[r][c] = (short)clampf(rintf(v * r0a), -QMAXF, QMAXF);
    }
    for (int i = tid; i < 144; i += 448) lw[i] = wq[i];
    if (tid < 16) lbsc[tid] = bias[tid] * sc;
    __syncthreads();
    const int myrow = tid / 56, p0 = (tid - myrow * 56) * 4;
    float acc[4][16];
#pragma unroll
    for (int px = 0; px < 4; px++)
#pragma unroll
        for (int co = 0; co < 16; co++) acc[px][co] = 0.f;
#pragma unroll
    for (int ky = 0; ky < 3; ky++) {
        const short* rp = &lx[myrow + ky][0];
        float xf[6];
        short4 v = *(const short4*)(rp + p0);
        xf[1] = (float)v.x; xf[2] = (float)v.y;
        xf[3] = (float)v.z; xf[4] = (float)v.w;
        xf[0] = (p0 > 0)   ? (float)rp[p0 - 1] : 0.f;
        xf[5] = (p0 < 220) ? (float)rp[p0 + 4] : 0.f;
#pragma unroll
        for (int kx = 0; kx < 3; kx++) {
            const float* wp = &lw[(ky * 3 + kx) * 16];
#pragma unroll
            for (int px = 0; px < 4; px++) {
                float xv = xf[px + kx];
#pragma unroll
                for (int co = 0; co < 16; co++) acc[px][co] = fmaf(xv, wp[co], acc[px][co]);
            }
        }
    }
    const int orow = r0 + myrow;
    const size_t obase = ((size_t)b * 224 + orow) * 224 + p0;   // pixel index
#pragma unroll
    for (int px = 0; px < 4; px++) {
        uint pk[8];
#pragma unroll
        for (int co = 0; co < 16; co++) {
            float xi = clampf(rintf(fmaf(acc[px][co], sc, lbsc[co])), -32768.f, 32767.f);
            float slope = rintf(xi * 1.703125f);
            float gate = clampf(slope + three, 0.f, six);
            float k = clampf(rintf(xi * gate * r6v), -QMAXF, QMAXF);
            int cd = (int)clampf(rintf(k * rq1), -QMAXF, QMAXF);
            if (co & 1) pk[co >> 1] |= ((uint)cd) << 16;
            else        pk[co >> 1] = (uint)cd & 0xffffu;
        }
        uint4* dst = (uint4*)(out + (obase + px) * 16);
        dst[0] = make_uint4(pk[0], pk[1], pk[2], pk[3]);
        dst[1] = make_uint4(pk[4], pk[5], pk[6], pk[7]);
    }
}

// ---------------- conv2/conv3 epilogue helpers (all by VALUE — nothing address-taken) ----------------
__device__ __forceinline__ int epi_one(float s, float bsc1, float gs2, float three,
                                       float six, float r6v, float rq) {
    float xi = clampf(rintf(fmaf(s, gs2, bsc1)), -32768.f, 32767.f);
    float slope = rintf(xi * 1.703125f);
    float gate = clampf(slope + three, 0.f, six);
    float k = clampf(rintf(xi * gate * r6v), -QMAXF, QMAXF);
    return (int)clampf(rintf(k * rq), -QMAXF, QMAXF);
}
__device__ __forceinline__ float pool_one(float s, float bsc1, float gs2, float three,
                                          float six, float r6v) {
    float xi = clampf(rintf(fmaf(s, gs2, bsc1)), -32768.f, 32767.f);
    float slope = rintf(xi * 1.703125f);
    float gate = clampf(slope + three, 0.f, six);
    return clampf(rintf(xi * gate * r6v), -QMAXF, QMAXF);
}
__device__ __forceinline__ uint2 epi_codes(f32x4 A0, f32x4 A1, f32x4 A2, f32x4 A3,
        f32x4 bscv, float gs2, float three, float six, float r6v, float rq) {
    int c0 = epi_one((A0[0] + A1[0]) + (A2[0] + A3[0]), bscv[0], gs2, three, six, r6v, rq);
    int c1 = epi_one((A0[1] + A1[1]) + (A2[1] + A3[1]), bscv[1], gs2, three, six, r6v, rq);
    int c2 = epi_one((A0[2] + A1[2]) + (A2[2] + A3[2]), bscv[2], gs2, three, six, r6v, rq);
    int c3 = epi_one((A0[3] + A1[3]) + (A2[3] + A3[3]), bscv[3], gs2, three, six, r6v, rq);
    uint2 st;
    st.x = ((uint)c0 & 0xffffu) | ((uint)c1 << 16);
    st.y = ((uint)c2 & 0xffffu) | ((uint)c3 << 16);
    return st;
}
__device__ __forceinline__ f32x4 epi_pool(f32x4 A0, f32x4 A1, f32x4 A2, f32x4 A3,
        f32x4 wsum, f32x4 bscv, float gs2, float three, float six, float r6v) {
    wsum[0] += pool_one((A0[0] + A1[0]) + (A2[0] + A3[0]), bscv[0], gs2, three, six, r6v);
    wsum[1] += pool_one((A0[1] + A1[1]) + (A2[1] + A3[1]), bscv[1], gs2, three, six, r6v);
    wsum[2] += pool_one((A0[2] + A1[2]) + (A2[2] + A3[2]), bscv[2], gs2, three, six, r6v);
    wsum[3] += pool_one((A0[3] + A1[3]) + (A2[3] + A3[3]), bscv[3], gs2, three, six, r6v);
    return wsum;
}

#define MFMA16(d, bb, aa, cc) d = __builtin_amdgcn_mfma_f32_16x16x32_bf16(bb, aa, cc, 0, 0, 0)

// One output tile (16 px x 16 co, K=288): 9 taps x 2 passes into 4 named chains.
#define TILE(A0_, A1_, A2_, A3_, CG) do {                                        \
    short8v x0 = *(const short8v*)(Ab[0] + 512 * (CG));                          \
    short8v x1 = *(const short8v*)(Ab[1] + 512 * (CG));                          \
    MFMA16(A0_, B1[0], x0, Z);   MFMA16(A2_, B2[0], x0, Z);                      \
    MFMA16(A1_, B1[1], x1, Z);   MFMA16(A3_, B2[1], x1, Z);                      \
    short8v x2 = *(const short8v*)(Ab[2] + 512 * (CG));                          \
    MFMA16(A0_, B1[2], x2, A0_); MFMA16(A2_, B2[2], x2, A2_);                    \
    short8v x3 = *(const short8v*)(Ab[2] + 3584 + 512 * (CG));                   \
    MFMA16(A1_, B1[3], x3, A1_); MFMA16(A3_, B2[3], x3, A3_);                    \
    short8v x4 = *(const short8v*)(Ab[3] + 3584 + 512 * (CG));                   \
    MFMA16(A0_, B1[4], x4, A0_); MFMA16(A2_, B2[4], x4, A2_);                    \
    short8v x5 = *(const short8v*)(Ab[4] + 3584 + 512 * (CG));                   \
    MFMA16(A1_, B1[5], x5, A1_); MFMA16(A3_, B2[5], x5, A3_);                    \
    short8v x6 = *(const short8v*)(Ab[4] + 7168 + 512 * (CG));                   \
    MFMA16(A0_, B1[6], x6, A0_); MFMA16(A2_, B2[6], x6, A2_);                    \
    short8v x7 = *(const short8v*)(Ab[5] + 7168 + 512 * (CG));                   \
    MFMA16(A1_, B1[7], x7, A1_); MFMA16(A3_, B2[7], x7, A3_);                    \
    short8v x8 = *(const short8v*)(Ab[6] + 7168 + 512 * (CG));                   \
    MFMA16(A0_, B1[8], x8, A0_); MFMA16(A2_, B2[8], x8, A2_);                    \
} while (0)

#define EPI(A0_, A1_, A2_, A3_, CGI) do {                                        \
    if (!POOL) {                                                                 \
        uint2 st = epi_codes(A0_, A1_, A2_, A3_, bscv, gs2, three, six, r6v, rq);\
        *(uint2*)(opb + (CGI) * 256) = st;                                       \
    } else {                                                                     \
        wsum = epi_pool(A0_, A1_, A2_, A3_, wsum, bscv, gs2, three, six, r6v);   \
    }                                                                            \
} while (0)

// ---------------- conv2/conv3: MFMA implicit GEMM (D = W * X), 4 rows x 112 cols ----------------
// Round-4 geometry (proven 86.8us, clean memory) + software-pipelined epilogue:
// tile cg's MFMA overlaps epilogue of tile cg-1 via two named accumulator sets.
template <bool POOL>
__global__ __launch_bounds__(256, 3) void conv16_kernel(
        const ushort* __restrict__ in, const ushort* __restrict__ wq,
        const float* __restrict__ bias, const float* __restrict__ asc,
        const float* __restrict__ shf, const float* __restrict__ wsb,
        ushort* __restrict__ out, float* __restrict__ partial,
        int aidx, int sidx, int widx) {
    const int bid = blockIdx.x;
    const int b = bid / 112, rem = bid % 112, rg = rem >> 1, ch = rem & 1;
    const int r0 = rg * 4, c0 = ch * 112;
    const int tid = threadIdx.x;
    const int l = tid & 63, w = tid >> 6;
    const int l15 = l & 15, lk = l >> 4;

    __shared__ alignas(16) ushort lsx[684 * 32];        // 43,776 B (6 rows x 114 cols)
    __shared__ float lred[4][16];

    const float ain = asc[aidx];
    const float anext = asc[aidx + 1];
    const float wsc = wsb[widx];
    const float sh = clampf(rintf(shf[sidx]), 4.f, 12.f);
    const float sc = exp2f(sh), osc = exp2f(-sh);
    const float three = 3.f * sc, six = 6.f * sc;
    const float gs2 = (ain * wsc) * sc;
    const float r6v = 1.0f / six;
    const float rq = osc / anext;
    f32x4 bscv;
    bscv[0] = bias[lk * 4 + 0] * sc;
    bscv[1] = bias[lk * 4 + 1] * sc;
    bscv[2] = bias[lk * 4 + 2] * sc;
    bscv[3] = bias[lk * 4 + 3] * sc;

    // ---- W fragments (A operand of mfma): pass1 [wh|wl], pass2 [wl|wh] ----
    short8v B1[9], B2[9];
#pragma unroll
    for (int t = 0; t < 9; t++) {
        B1[t] = *(const short8v*)(wq + ((t * 4 + lk) * 16 + l15) * 8);
        B2[t] = *(const short8v*)(wq + ((t * 4 + (lk ^ 2)) * 16 + l15) * 8);
    }

    // ---- stage x tile: 6 rows x 114 cols; RTZ bf16 hi/lo split (exact) ----
#pragma unroll
    for (int it = 0; it < 3; it++) {
        int e = tid + it * 256;
        if (e < 684) {
            int r = e / 114, cc = e - r * 114;
            int ir = r0 - 1 + r, ic = c0 - 1 + cc;
            uint4 va = make_uint4(0u, 0u, 0u, 0u), vb = make_uint4(0u, 0u, 0u, 0u);
            if ((unsigned)ir < 224u && (unsigned)ic < 224u) {
                const uint4* src = (const uint4*)(in + (((size_t)b * 224 + ir) * 224 + ic) * 16);
                va = src[0]; vb = src[1];
            }
            uint uu[8] = {va.x, va.y, va.z, va.w, vb.x, vb.y, vb.z, vb.w};
            uint hi[8], lo[8];
#pragma unroll
            for (int i = 0; i < 8; i++) {
                int e0 = (int)(short)(uu[i] & 0xffffu);
                int e1 = (int)uu[i] >> 16;
                float f0 = (float)e0, f1 = (float)e1;
                uint h0 = __float_as_uint(f0) & 0xffff0000u;
                uint h1 = __float_as_uint(f1) & 0xffff0000u;
                float l0f = f0 - __uint_as_float(h0);   // exact, fits bf16
                float l1f = f1 - __uint_as_float(h1);
                hi[i] = __builtin_amdgcn_perm(h1, h0, 0x07060302);
                lo[i] = __builtin_amdgcn_perm(__float_as_uint(l1f), __float_as_uint(l0f), 0x07060302);
            }
            int rot = (e >> 1) & 3;
            ushort* eb = lsx + e * 32;
            *(uint4*)(eb + ((0 ^ rot) << 3)) = make_uint4(hi[0], hi[1], hi[2], hi[3]);
            *(uint4*)(eb + ((1 ^ rot) << 3)) = make_uint4(hi[4], hi[5], hi[6], hi[7]);
            *(uint4*)(eb + ((2 ^ rot) << 3)) = make_uint4(lo[0], lo[1], lo[2], lo[3]);
            *(uint4*)(eb + ((3 ^ rot) << 3)) = make_uint4(lo[4], lo[5], lo[6], lo[7]);
        }
    }
    __syncthreads();

    // ---- per-lane swizzled base pointers (rot invariant under +112-entry ky step
    //      and +16-entry cg step); indexed with literals only ----
    const ushort* Ab[7];
#pragma unroll
    for (int m = 0; m < 7; m++) {
        int e = w * 114 + l15 + m;
        Ab[m] = lsx + e * 32 + ((lk ^ ((e >> 1) & 3)) << 3);
    }

    f32x4 wsum = {0.f, 0.f, 0.f, 0.f};
    const int orow = r0 + w;
    ushort* opb = out + (((size_t)b * 224 + orow) * 224 + c0 + l15) * 16 + lk * 4;

    const f32x4 Z = {0.f, 0.f, 0.f, 0.f};
    f32x4 eA0, eA1, eA2, eA3;   // even-cg set
    f32x4 oA0, oA1, oA2, oA3;   // odd-cg set

    TILE(eA0, eA1, eA2, eA3, 0);
    TILE(oA0, oA1, oA2, oA3, 1);
    EPI(eA0, eA1, eA2, eA3, 0);
    TILE(eA0, eA1, eA2, eA3, 2);
    EPI(oA0, oA1, oA2, oA3, 1);
    TILE(oA0, oA1, oA2, oA3, 3);
    EPI(eA0, eA1, eA2, eA3, 2);
    TILE(eA0, eA1, eA2, eA3, 4);
    EPI(oA0, oA1, oA2, oA3, 3);
    TILE(oA0, oA1, oA2, oA3, 5);
    EPI(eA0, eA1, eA2, eA3, 4);
    TILE(eA0, eA1, eA2, eA3, 6);
    EPI(oA0, oA1, oA2, oA3, 5);
    EPI(eA0, eA1, eA2, eA3, 6);

    if (POOL) {
#pragma unroll
        for (int r = 0; r < 4; r++) {
            float v = wsum[r] * osc;
            v += __shfl_xor(v, 1);
            v += __shfl_xor(v, 2);
            v += __shfl_xor(v, 4);
            v += __shfl_xor(v, 8);
            if (l15 == 0) lred[w][lk * 4 + r] = v;
        }
        __syncthreads();
        if (tid < 16) {
            partial[((size_t)b * 112 + rem) * 16 + tid] =
                lred[0][tid] + lred[1][tid] + lred[2][tid] + lred[3][tid];
        }
    }
}

// ---------------- pool-reduce + quantized FC ----------------
__global__ __launch_bounds__(1024) void fc_kernel(const float* __restrict__ partial,
        const float* __restrict__ wq, const float* __restrict__ fb,
        const float* __restrict__ asc, float* __restrict__ out) {
    __shared__ float xq[64][16];
    const int t = threadIdx.x;
    const float a3 = asc[3];
    {
        int b = t >> 4, c = t & 15;
        const float* p = partial + ((size_t)b * 112) * 16 + c;
        float s = 0.f;
        for (int i = 0; i < 112; i++) s += p[i * 16];
        float pooled = s / 50176.0f;
        xq[b][c] = fq_code(pooled, a3) * a3;
    }
    __syncthreads();
    if (t < 640) {
        int b = t / 10, o = t - (t / 10) * 10;
        float s = 0.f;
#pragma unroll
        for (int c = 0; c < 16; c++) s += xq[b][c] * wq[o * 16 + c];
        out[t] = s + fb[o];
    }
}

extern "C" void kernel_launch(void* const* d_in, const int* in_sizes, int n_in,
                              void* d_out, int out_size, void* d_ws, size_t ws_size,
                              hipStream_t stream) {
    const float* x   = (const float*)d_in[0];
    const float* c1w = (const float*)d_in[1];
    const float* c1b = (const float*)d_in[2];
    const float* c2w = (const float*)d_in[3];
    const float* c2b = (const float*)d_in[4];
    const float* c3w = (const float*)d_in[5];
    const float* c3b = (const float*)d_in[6];
    const float* fcw = (const float*)d_in[7];
    const float* fcb = (const float*)d_in[8];
    const float* asc = (const float*)d_in[9];
    const float* shf = (const float*)d_in[10];

    char* ws = (char*)d_ws;
    size_t off = 0;
    auto alloc = [&](size_t bytes) -> void* {
        void* p = ws + off;
        off = (off + bytes + 255) & ~(size_t)255;
        return p;
    };
    float*  wq1     = (float*)alloc(144 * 4);
    ushort* wq2b    = (ushort*)alloc(4608 * 2);
    ushort* wq3b    = (ushort*)alloc(4608 * 2);
    float*  wqfc    = (float*)alloc(160 * 4);
    float*  wsb     = (float*)alloc(4 * 4);
    float*  partial = (float*)alloc(64 * 112 * 16 * 4);
    ushort* actA    = (ushort*)alloc(51380224ull * 2);
    ushort* actB    = (ushort*)alloc(51380224ull * 2);

    prep_kernel<<<4, 256, 0, stream>>>(c1w, c2w, c3w, fcw, asc, wq1, wq2b, wq3b, wqfc, wsb);
    conv1_kernel<<<1792, 448, 0, stream>>>(x, wq1, c1b, asc, shf, actA);
    conv16_kernel<false><<<7168, 256, 0, stream>>>(actA, wq2b, c2b, asc, shf, wsb,
                                                   actB, nullptr, 1, 1, 0);
    conv16_kernel<true ><<<7168, 256, 0, stream>>>(actB, wq3b, c3b, asc, shf, wsb,
                                                   nullptr, partial, 2, 2, 1);
    fc_kernel<<<1, 1024, 0, stream>>>(partial, wqfc, fcb, asc, (float*)d_out);
}